// Round 15
// baseline (285.028 us; speedup 1.0000x reference)
//
#include <hip/hip_runtime.h>
#include <hip/hip_fp16.h>
#include <math.h>

// Problem constants (match reference file)
constexpr int DG  = 128;
constexpr int DIN = 128;
constexpr int DH  = 64;
constexpr int DFC = 32;
constexpr int DC  = 10;
constexpr int CAP  = 80;    // adjacency capacity/node (deg ~ Poisson(32); P(>80)~1e-13)
constexpr int NPB  = 64;    // nodes per bucket (power of 2 -> shift addressing)
constexpr int NB   = 1563;  // ceil(100000/64) buckets
constexpr int ABLK = 256;   // edge-chunk blocks (hist/binplace use identical partition)
constexpr int SCAP = 2560;  // staging capacity per bucket (avg fill ~2048, +11 sigma)

typedef _Float16 f16;
typedef f16  f16x8 __attribute__((ext_vector_type(8)));
typedef float f32x4 __attribute__((ext_vector_type(4)));

// XOR-swizzled byte offset within a 128-B LDS row (bank-conflict-free frag reads)
__device__ __forceinline__ int swz(int row, int byte_in_row) {
    return row * 128 + (byte_in_row ^ ((row & 7) << 4));
}

// ---------------- build 1: per-block LDS histogram, bucket-major output ----------------
__global__ __launch_bounds__(256) void k_hist(const int* __restrict__ src,
                                              const int* __restrict__ dst,
                                              int* __restrict__ histT,   // [NB][ABLK]
                                              int E, int EPB) {
    __shared__ int h[NB];
    for (int i = threadIdx.x; i < NB; i += 256) h[i] = 0;
    __syncthreads();
    int e0 = blockIdx.x * EPB, e1 = min(e0 + EPB, E);
    for (int i = e0 + threadIdx.x; i < e1; i += 256) {
        int u = src[i], v = dst[i];
        atomicAdd(&h[v >> 6], 1);
        atomicAdd(&h[u >> 6], 1);
    }
    __syncthreads();
    for (int i = threadIdx.x; i < NB; i += 256)
        histT[(size_t)i * ABLK + blockIdx.x] = h[i];
}

// ---------------- build 2: per-bucket LDS scan -> bases + totals (+pool zero) ----------------
__global__ __launch_bounds__(256) void k_expand(const int* __restrict__ histT,
                                                int* __restrict__ baseT,   // [NB][ABLK]
                                                int* __restrict__ ecnt,
                                                float* __restrict__ sums,
                                                int* __restrict__ cnts) {
    __shared__ int s[256];
    int b = blockIdx.x, t = threadIdx.x;
    int v = histT[(size_t)b * ABLK + t];
    s[t] = v;
    __syncthreads();
    for (int o = 1; o < 256; o <<= 1) {
        int tv = (t >= o) ? s[t - o] : 0;
        __syncthreads();
        s[t] += tv;
        __syncthreads();
    }
    int incl = s[t];
    baseT[(size_t)b * ABLK + t] = b * SCAP + incl - v;   // exclusive + bucket offset
    if (t == 255) ecnt[b] = min(incl, SCAP);
    int gid = b * 256 + t;
    if (gid < DG * DH) sums[gid] = 0.0f;
    if (gid < DG) cnts[gid] = 0;
}

// ---------------- build 3: place packed entries into bucket-grouped staging ----------------
__global__ __launch_bounds__(256) void k_binplace(const int* __restrict__ src,
                                                  const int* __restrict__ dst,
                                                  const int* __restrict__ baseT,
                                                  int* __restrict__ staging,
                                                  int E, int EPB) {
    __shared__ int lcnt[NB];
    __shared__ int lbase[NB];
    int blk = blockIdx.x;
    for (int i = threadIdx.x; i < NB; i += 256) {
        lcnt[i]  = 0;
        lbase[i] = baseT[(size_t)i * ABLK + blk];
    }
    __syncthreads();
    int e0 = blk * EPB, e1 = min(e0 + EPB, E);
    for (int i = e0 + threadIdx.x; i < e1; i += 256) {
        int u = src[i], v = dst[i];
        int bv = v >> 6, bu = u >> 6;
        int rv = atomicAdd(&lcnt[bv], 1);
        int sv = lbase[bv] + rv;
        if (sv < (bv + 1) * SCAP) staging[sv] = ((v & 63) << 17) | u;
        int ru = atomicAdd(&lcnt[bu], 1);
        int su = lbase[bu] + ru;
        if (su < (bu + 1) * SCAP) staging[su] = ((u & 63) << 17) | v;
    }
}

// ---------------- build 4: one block per bucket -> adj rows + cnt + dinv ----------------
__global__ __launch_bounds__(256) void k_rows(const int* __restrict__ staging,
                                              const int* __restrict__ ecnt,
                                              int* __restrict__ adj,
                                              int* __restrict__ cnt,
                                              float* __restrict__ dinv,
                                              int N) {
    __shared__ int rows[NPB * CAP];   // 20.5 KB
    __shared__ int cur[NPB];
    int b = blockIdx.x;
    int nbase = b * NPB;
    int nn = min(NPB, N - nbase);
    if (nn <= 0) return;
    for (int i = threadIdx.x; i < nn; i += 256) cur[i] = 0;
    __syncthreads();
    int s0 = b * SCAP, s1 = s0 + ecnt[b];
    for (int i = s0 + threadIdx.x; i < s1; i += 256) {
        int e  = staging[i];
        int vl = e >> 17;
        int u  = e & 0x1FFFF;
        int p  = atomicAdd(&cur[vl], 1);
        if (p < CAP) rows[vl * CAP + p] = u;
    }
    __syncthreads();
    for (int s = threadIdx.x; s < nn * CAP; s += 256) {
        int node = s / CAP, p = s - node * CAP;
        if (p < min(cur[node], CAP))
            adj[(size_t)(nbase + node) * CAP + p] = rows[s];
    }
    for (int i = threadIdx.x; i < nn; i += 256) {
        int c = cur[i];
        cnt[nbase + i]  = c;
        dinv[nbase + i] = rsqrtf(1.0f + (float)c);
    }
}

// ---------------- weight prep: transpose + f16 convert, [col][k] layout ----------------
__global__ __launch_bounds__(256) void k_wprep(const float* __restrict__ Wi,
                                               const float* __restrict__ W1,
                                               const float* __restrict__ W2,
                                               f16* __restrict__ WiT,
                                               f16* __restrict__ W1T,
                                               f16* __restrict__ W2T) {
    int t = blockIdx.x * 256 + threadIdx.x;
    int stride = gridDim.x * 256;
    for (int i = t; i < DH * DIN; i += stride) {      // WiT[c][k] = Wi[k][c]
        int c = i >> 7, k = i & 127;
        WiT[i] = (f16)Wi[k * DH + c];
    }
    for (int i = t; i < DH * DH; i += stride) {       // W1T/W2T[c][k]
        int c = i >> 6, k = i & 63;
        W1T[i] = (f16)W1[k * DH + c];
        W2T[i] = (f16)W2[k * DH + c];
    }
}

// ---------------- MFMA fused: h0 = relu(x@Wi+bi) (LDS, wave-private); out = f16((h0@W1)*dinv) ----------------
__global__ __launch_bounds__(256) void k_lin2(const float* __restrict__ x,
                                              const f16* __restrict__ WiT,
                                              const float* __restrict__ bi,
                                              const f16* __restrict__ W1T,
                                              const float* __restrict__ dinv,
                                              __half* __restrict__ out, int n) {
    __shared__ f16 h0[4 * 16 * 64];   // 8 KB, 2 KB per wave
    int t = threadIdx.x, lane = t & 63, w = t >> 6;
    int rb = blockIdx.x * 64 + w * 16;
    if (rb >= n) return;
    int lr = lane & 15;   // A/D row | B/D col
    int lg = lane >> 4;   // k-group / row-group
    f16x8 a[4];
    const float* xrow = x + (size_t)(rb + lr) * DIN + lg * 8;
#pragma unroll
    for (int k0 = 0; k0 < 4; k0++) {
        float4 f0 = *(const float4*)(xrow + k0 * 32);
        float4 f1 = *(const float4*)(xrow + k0 * 32 + 4);
        a[k0][0] = (f16)f0.x; a[k0][1] = (f16)f0.y; a[k0][2] = (f16)f0.z; a[k0][3] = (f16)f0.w;
        a[k0][4] = (f16)f1.x; a[k0][5] = (f16)f1.y; a[k0][6] = (f16)f1.z; a[k0][7] = (f16)f1.w;
    }
    char* hwb = (char*)(h0 + w * 16 * 64);
#pragma unroll
    for (int cb = 0; cb < 4; cb++) {
        f32x4 acc = {0.f, 0.f, 0.f, 0.f};
        const f16* wt = WiT + (cb * 16 + lr) * DIN + lg * 8;
#pragma unroll
        for (int k0 = 0; k0 < 4; k0++) {
            f16x8 bf = *(const f16x8*)(wt + k0 * 32);
            acc = __builtin_amdgcn_mfma_f32_16x16x32_f16(a[k0], bf, acc, 0, 0, 0);
        }
        float bv = bi[cb * 16 + lr];
#pragma unroll
        for (int r = 0; r < 4; r++) {
            int row = lg * 4 + r;
            *(f16*)(hwb + swz(row, (cb * 16 + lr) * 2)) = (f16)fmaxf(acc[r] + bv, 0.0f);
        }
    }
    f16x8 a2[2];
#pragma unroll
    for (int k0 = 0; k0 < 2; k0++)
        a2[k0] = *(const f16x8*)(hwb + swz(lr, k0 * 64 + lg * 16));
    float dv[4];
#pragma unroll
    for (int r = 0; r < 4; r++) dv[r] = dinv[rb + lg * 4 + r];
#pragma unroll
    for (int cb = 0; cb < 4; cb++) {
        f32x4 acc = {0.f, 0.f, 0.f, 0.f};
        const f16* wt = W1T + (cb * 16 + lr) * DH + lg * 8;
        acc = __builtin_amdgcn_mfma_f32_16x16x32_f16(a2[0], *(const f16x8*)(wt), acc, 0, 0, 0);
        acc = __builtin_amdgcn_mfma_f32_16x16x32_f16(a2[1], *(const f16x8*)(wt + 32), acc, 0, 0, 0);
#pragma unroll
        for (int r = 0; r < 4; r++)
            out[(size_t)(rb + lg * 4 + r) * DH + cb * 16 + lr] = __float2half(acc[r] * dv[r]);
    }
}

// ---------------- gather inner (round-12 proven form): 8 loads in flight ----------------
__device__ __forceinline__ void gather_node(int v, const int* __restrict__ cnt,
                                            const int* __restrict__ adj,
                                            const char* __restrict__ xb,
                                            int lane, int half_id, int fpo,
                                            float& ax, float& ay) {
    int len = min(cnt[v], CAP);
    const int* row = adj + (size_t)v * CAP;
    int idx = 0;
    if (lane < len) idx = row[lane];
    int len64 = min(len, 64);
    ax = 0.f; ay = 0.f;
    int k = half_id;
    for (; k + 14 < len64; k += 16) {
        int u0 = __shfl(idx, k);
        int u1 = __shfl(idx, k + 2);
        int u2 = __shfl(idx, k + 4);
        int u3 = __shfl(idx, k + 6);
        int u4 = __shfl(idx, k + 8);
        int u5 = __shfl(idx, k + 10);
        int u6 = __shfl(idx, k + 12);
        int u7 = __shfl(idx, k + 14);
        __half2 h0 = *(const __half2*)(xb + ((u0 << 7) | fpo));
        __half2 h1 = *(const __half2*)(xb + ((u1 << 7) | fpo));
        __half2 h2 = *(const __half2*)(xb + ((u2 << 7) | fpo));
        __half2 h3 = *(const __half2*)(xb + ((u3 << 7) | fpo));
        h0 = __hadd2(h0, *(const __half2*)(xb + ((u4 << 7) | fpo)));
        h1 = __hadd2(h1, *(const __half2*)(xb + ((u5 << 7) | fpo)));
        h2 = __hadd2(h2, *(const __half2*)(xb + ((u6 << 7) | fpo)));
        h3 = __hadd2(h3, *(const __half2*)(xb + ((u7 << 7) | fpo)));
        float2 f0 = __half22float2(h0);
        float2 f1 = __half22float2(h1);
        float2 f2 = __half22float2(h2);
        float2 f3 = __half22float2(h3);
        ax += (f0.x + f1.x) + (f2.x + f3.x);
        ay += (f0.y + f1.y) + (f2.y + f3.y);
    }
    for (; k < len64; k += 2) {
        int u0 = __shfl(idx, k);
        float2 f0 = __half22float2(*(const __half2*)(xb + ((u0 << 7) | fpo)));
        ax += f0.x; ay += f0.y;
    }
    for (int j = 64 + half_id; j < len; j += 2) {  // rare tail (deg > 64)
        float2 f0 = __half22float2(*(const __half2*)(xb + ((row[j] << 7) | fpo)));
        ax += f0.x; ay += f0.y;
    }
    ax += __shfl_xor(ax, 32);
    ay += __shfl_xor(ay, 32);
}

// ---------------- fused gather1 + conv2 matmul (2-wave blocks, 8 nodes/wave) ----------------
__global__ __launch_bounds__(128) void k_g1(const int* __restrict__ cnt,
                                            const int* __restrict__ adj,
                                            const __half2* __restrict__ xws,
                                            const float* __restrict__ dinv,
                                            const float* __restrict__ b,
                                            const f16* __restrict__ W2T,
                                            __half* __restrict__ out, int n) {
    __shared__ char wb[2048];   // one 16-row x 128-B swizzled tile per block
    int t = threadIdx.x, lane = t & 63, w = t >> 6;
    int rb = blockIdx.x * 16;
    if (rb >= n) return;
    int half_id = lane >> 5, fp = lane & 31, fpo = fp << 2;
    const char* xb = (const char*)xws;
    float2 bb = ((const float2*)b)[fp];
#pragma unroll 1
    for (int i = 0; i < 8; i++) {
        int row = w * 8 + i;          // this wave's rows in the tile
        int v = rb + row;
        float ax, ay;
        gather_node(v, cnt, adj, xb, lane, half_id, fpo, ax, ay);
        if (half_id == 0) {
            float2 s  = __half22float2(*(const __half2*)(xb + ((v << 7) | fpo)));
            float  dv = dinv[v];
            __half2 hh = __floats2half2_rn(fmaxf(dv * (ax + s.x) + bb.x, 0.0f),
                                           fmaxf(dv * (ay + s.y) + bb.y, 0.0f));
            *(__half2*)(wb + swz(row, fpo)) = hh;
        }
    }
    __syncthreads();
    // MFMA phase: wave w computes column-blocks 2w, 2w+1 of the 16x64 tile
    int lr = lane & 15, lg = lane >> 4;
    f16x8 a0 = *(const f16x8*)(wb + swz(lr, lg * 16));
    f16x8 a1 = *(const f16x8*)(wb + swz(lr, 64 + lg * 16));
    float dvr[4];
#pragma unroll
    for (int r = 0; r < 4; r++) dvr[r] = dinv[rb + lg * 4 + r];
#pragma unroll
    for (int cbi = 0; cbi < 2; cbi++) {
        int cb = w * 2 + cbi;
        const f16* wt = W2T + (cb * 16 + lr) * DH + lg * 8;
        f32x4 acc = {0.f, 0.f, 0.f, 0.f};
        acc = __builtin_amdgcn_mfma_f32_16x16x32_f16(a0, *(const f16x8*)(wt), acc, 0, 0, 0);
        acc = __builtin_amdgcn_mfma_f32_16x16x32_f16(a1, *(const f16x8*)(wt + 32), acc, 0, 0, 0);
#pragma unroll
        for (int r = 0; r < 4; r++)
            out[(size_t)(rb + lg * 4 + r) * DH + cb * 16 + lr] = __float2half(acc[r] * dvr[r]);
    }
}

// ---------------- fused gather2 + pooling (2-wave blocks, 8 nodes/wave) ----------------
__global__ __launch_bounds__(128) void k_g2(const int* __restrict__ cnt,
                                            const int* __restrict__ adj,
                                            const __half2* __restrict__ xws,
                                            const float* __restrict__ dinv,
                                            const float* __restrict__ b,
                                            const int* __restrict__ batch,
                                            float* __restrict__ sums,
                                            int* __restrict__ cnts, int n) {
    int t = threadIdx.x, lane = t & 63, w = t >> 6;
    int rb = blockIdx.x * 16 + w * 8;   // each wave: 8 contiguous nodes
    if (rb >= n) return;
    int half_id = lane >> 5, fp = lane & 31, fpo = fp << 2;
    const char* xb = (const char*)xws;
    float2 bb = ((const float2*)b)[fp];
    int curg = -1, c = 0;
    float pax = 0.f, pay = 0.f;
#pragma unroll 1
    for (int i = 0; i < 8; i++) {
        int v = rb + i;
        float ax, ay;
        gather_node(v, cnt, adj, xb, lane, half_id, fpo, ax, ay);
        float2 s  = __half22float2(*(const __half2*)(xb + ((v << 7) | fpo)));
        float  dv = dinv[v];
        float ox = fmaxf(dv * (ax + s.x) + bb.x, 0.0f);
        float oy = fmaxf(dv * (ay + s.y) + bb.y, 0.0f);
        int g = batch[v];
        if (g != curg) {
            if (curg >= 0 && half_id == 0) {
                atomicAdd(&sums[curg * DH + 2 * fp],     pax);
                atomicAdd(&sums[curg * DH + 2 * fp + 1], pay);
                if (lane == 0) atomicAdd(&cnts[curg], c);
            }
            curg = g; pax = 0.f; pay = 0.f; c = 0;
        }
        if (half_id == 0) { pax += ox; pay += oy; }
        c++;
    }
    if (curg >= 0 && half_id == 0) {
        atomicAdd(&sums[curg * DH + 2 * fp],     pax);
        atomicAdd(&sums[curg * DH + 2 * fp + 1], pay);
        if (lane == 0) atomicAdd(&cnts[curg], c);
    }
}

// ---------------- head: mean, fc1+relu, fc2, log_softmax ----------------
__global__ __launch_bounds__(64) void k_head(const float* __restrict__ sums,
                                             const int* __restrict__ cnts,
                                             const float* __restrict__ Wf1,
                                             const float* __restrict__ bf1,
                                             const float* __restrict__ Wf2,
                                             const float* __restrict__ bf2,
                                             float* __restrict__ out) {
    int g = blockIdx.x, lane = threadIdx.x;
    float cnt    = (float)max(cnts[g], 1);
    float pooled = sums[g * DH + lane] / cnt;
    float acc = (lane < DFC) ? bf1[lane] : 0.f;
    for (int k = 0; k < DH; k++) {
        float pk = __shfl(pooled, k);
        if (lane < DFC) acc = fmaf(pk, Wf1[k * DFC + lane], acc);
    }
    float gv = fmaxf(acc, 0.f);
    float acc2 = (lane < DC) ? bf2[lane] : 0.f;
    for (int k = 0; k < DFC; k++) {
        float gk = __shfl(gv, k);
        if (lane < DC) acc2 = fmaf(gk, Wf2[k * DC + lane], acc2);
    }
    float v = (lane < DC) ? acc2 : -INFINITY;
    float m = v;
    for (int o = 8; o; o >>= 1) m = fmaxf(m, __shfl_xor(m, o));
    float e = (lane < DC) ? expf(v - m) : 0.f;
    float s = e;
    for (int o = 8; o; o >>= 1) s += __shfl_xor(s, o);
    if (lane < DC) out[g * DC + lane] = v - m - logf(s);
}

extern "C" void kernel_launch(void* const* d_in, const int* in_sizes, int n_in,
                              void* d_out, int out_size, void* d_ws, size_t ws_size,
                              hipStream_t stream) {
    const float* x    = (const float*)d_in[0];
    const int*   ei   = (const int*)d_in[1];
    const int*   batch= (const int*)d_in[2];
    const float* W_in = (const float*)d_in[3];
    const float* b_in = (const float*)d_in[4];
    const float* W1   = (const float*)d_in[5];
    const float* b1   = (const float*)d_in[6];
    const float* W2   = (const float*)d_in[7];
    const float* b2   = (const float*)d_in[8];
    const float* Wf1  = (const float*)d_in[9];
    const float* bf1  = (const float*)d_in[10];
    const float* Wf2  = (const float*)d_in[11];
    const float* bf2  = (const float*)d_in[12];
    float* out = (float*)d_out;

    const int E = in_sizes[1] / 2;      // 1,600,000
    const int N = in_sizes[0] / DIN;    // 100,000
    const int* src = ei;
    const int* dst = ei + E;

    const int NBU = (N + NPB - 1) / NPB;        // buckets used (1563)
    const int EPB = (E + ABLK - 1) / ABLK;      // edges per hist/binplace block

    char* ws = (char*)d_ws;
    size_t off = 0;
    auto alloc = [&](size_t bytes) -> void* {
        void* p = ws + off;
        off = (off + bytes + 255) & ~(size_t)255;
        return p;
    };
    int*    cnt     = (int*)   alloc((size_t)N * 4);
    float*  dinv    = (float*) alloc((size_t)N * 4);
    int*    adj     = (int*)   alloc((size_t)N * CAP * 4);      // 32 MB
    int*    histT   = (int*)   alloc((size_t)NB * ABLK * 4);    // 1.6 MB
    int*    baseT   = (int*)   alloc((size_t)NB * ABLK * 4);    // 1.6 MB
    int*    ecnt    = (int*)   alloc((size_t)NB * 4);
    int*    staging = (int*)   alloc((size_t)NB * SCAP * 4);    // 16 MB
    __half* hA      = (__half*)alloc((size_t)N * DH * 2);       // 12.8 MB (xws2)
    __half* hX      = (__half*)alloc((size_t)N * DH * 2);       // 12.8 MB (xws1)
    float*  sums    = (float*) alloc((size_t)DG * DH * 4);
    int*    cnts    = (int*)   alloc((size_t)DG * 4);
    f16*    WiT     = (f16*)   alloc((size_t)DH * DIN * 2);
    f16*    W1T     = (f16*)   alloc((size_t)DH * DH * 2);
    f16*    W2T     = (f16*)   alloc((size_t)DH * DH * 2);

    // weight prep (transpose + f16)
    k_wprep<<<32, 256, 0, stream>>>(W_in, W1, W2, WiT, W1T, W2T);

    // atomic-free adjacency build: hist(T) -> per-bucket scan(+pool zero) -> binplace -> rows
    k_hist<<<ABLK, 256, 0, stream>>>(src, dst, histT, E, EPB);
    k_expand<<<NB, 256, 0, stream>>>(histT, baseT, ecnt, sums, cnts);
    k_binplace<<<ABLK, 256, 0, stream>>>(src, dst, baseT, staging, E, EPB);
    k_rows<<<NBU, 256, 0, stream>>>(staging, ecnt, adj, cnt, dinv, N);

    // fused MFMA: h0 = relu(xWi+bi); xws1 = f16((h0@W1)*dinv)
    k_lin2<<<(N + 63) / 64, 256, 0, stream>>>(x, WiT, b_in, W1T, dinv, hX, N);

    // fused gather1 + conv2 matmul (2-wave blocks, 16 nodes/block)
    k_g1<<<(N + 15) / 16, 128, 0, stream>>>(cnt, adj, (const __half2*)hX, dinv, b1, W2T, hA, N);

    // fused gather2 + pooling (2-wave blocks, 16 nodes/block)
    k_g2<<<(N + 15) / 16, 128, 0, stream>>>(cnt, adj, (const __half2*)hA, dinv, b2, batch, sums, cnts, N);

    // head
    k_head<<<DG, 64, 0, stream>>>(sums, cnts, Wf1, bf1, Wf2, bf2, out);
}

// Round 16
// 256.750 us; speedup vs baseline: 1.1101x; 1.1101x over previous
//
#include <hip/hip_runtime.h>
#include <hip/hip_fp16.h>
#include <math.h>

// Problem constants (match reference file)
constexpr int DG  = 128;
constexpr int DIN = 128;
constexpr int DH  = 64;
constexpr int DFC = 32;
constexpr int DC  = 10;
constexpr int CAP  = 80;    // adjacency capacity/node (deg ~ Poisson(32); P(>80)~1e-13)
constexpr int NPB  = 64;    // nodes per bucket (power of 2 -> shift addressing)
constexpr int NB   = 1563;  // ceil(100000/64) buckets
constexpr int ABLK = 256;   // edge-chunk blocks (hist/binplace use identical partition)
constexpr int SCAP = 2560;  // staging capacity per bucket (avg fill ~2048, +11 sigma)

typedef _Float16 f16;
typedef f16  f16x8 __attribute__((ext_vector_type(8)));
typedef float f32x4 __attribute__((ext_vector_type(4)));

// XOR-swizzled byte offset within a 128-B LDS row (bank-conflict-free frag reads)
__device__ __forceinline__ int swz(int row, int byte_in_row) {
    return row * 128 + (byte_in_row ^ ((row & 7) << 4));
}

// ---------------- build 1: per-block LDS histogram, bucket-major output ----------------
__global__ __launch_bounds__(256) void k_hist(const int* __restrict__ src,
                                              const int* __restrict__ dst,
                                              int* __restrict__ histT,   // [NB][ABLK]
                                              int E, int EPB) {
    __shared__ int h[NB];
    for (int i = threadIdx.x; i < NB; i += 256) h[i] = 0;
    __syncthreads();
    int e0 = blockIdx.x * EPB, e1 = min(e0 + EPB, E);
    for (int i = e0 + threadIdx.x; i < e1; i += 256) {
        int u = src[i], v = dst[i];
        atomicAdd(&h[v >> 6], 1);
        atomicAdd(&h[u >> 6], 1);
    }
    __syncthreads();
    for (int i = threadIdx.x; i < NB; i += 256)
        histT[(size_t)i * ABLK + blockIdx.x] = h[i];
}

// ---------------- build 2: per-bucket LDS scan -> bases + totals (+pool zero, +weight prep) ----------------
__global__ __launch_bounds__(256) void k_expand(const int* __restrict__ histT,
                                                int* __restrict__ baseT,   // [NB][ABLK]
                                                int* __restrict__ ecnt,
                                                float* __restrict__ sums,
                                                int* __restrict__ cnts,
                                                const float* __restrict__ Wi,
                                                const float* __restrict__ W1,
                                                const float* __restrict__ W2,
                                                f16* __restrict__ WiT,
                                                f16* __restrict__ W1T,
                                                f16* __restrict__ W2T) {
    __shared__ int s[256];
    int b = blockIdx.x, t = threadIdx.x;
    int v = histT[(size_t)b * ABLK + t];
    s[t] = v;
    __syncthreads();
    for (int o = 1; o < 256; o <<= 1) {
        int tv = (t >= o) ? s[t - o] : 0;
        __syncthreads();
        s[t] += tv;
        __syncthreads();
    }
    int incl = s[t];
    baseT[(size_t)b * ABLK + t] = b * SCAP + incl - v;   // exclusive + bucket offset
    if (t == 255) ecnt[b] = min(incl, SCAP);
    int gid = b * 256 + t;
    if (gid < DG * DH) sums[gid] = 0.0f;
    if (gid < DG) cnts[gid] = 0;
    // folded weight prep (transpose + f16, [col][k] layout)
    if (gid < DH * DIN) {
        int c = gid >> 7, k = gid & 127;
        WiT[gid] = (f16)Wi[k * DH + c];
    }
    if (gid < DH * DH) {
        int c = gid >> 6, k = gid & 63;
        W1T[gid] = (f16)W1[k * DH + c];
        W2T[gid] = (f16)W2[k * DH + c];
    }
}

// ---------------- build 3: place packed entries into bucket-grouped staging ----------------
__global__ __launch_bounds__(256) void k_binplace(const int* __restrict__ src,
                                                  const int* __restrict__ dst,
                                                  const int* __restrict__ baseT,
                                                  int* __restrict__ staging,
                                                  int E, int EPB) {
    __shared__ int lcnt[NB];
    __shared__ int lbase[NB];
    int blk = blockIdx.x;
    for (int i = threadIdx.x; i < NB; i += 256) {
        lcnt[i]  = 0;
        lbase[i] = baseT[(size_t)i * ABLK + blk];
    }
    __syncthreads();
    int e0 = blk * EPB, e1 = min(e0 + EPB, E);
    for (int i = e0 + threadIdx.x; i < e1; i += 256) {
        int u = src[i], v = dst[i];
        int bv = v >> 6, bu = u >> 6;
        int rv = atomicAdd(&lcnt[bv], 1);
        int sv = lbase[bv] + rv;
        if (sv < (bv + 1) * SCAP) staging[sv] = ((v & 63) << 17) | u;
        int ru = atomicAdd(&lcnt[bu], 1);
        int su = lbase[bu] + ru;
        if (su < (bu + 1) * SCAP) staging[su] = ((u & 63) << 17) | v;
    }
}

// ---------------- build 4: one block per bucket -> adj rows + cnt + dinv ----------------
__global__ __launch_bounds__(256) void k_rows(const int* __restrict__ staging,
                                              const int* __restrict__ ecnt,
                                              int* __restrict__ adj,
                                              int* __restrict__ cnt,
                                              float* __restrict__ dinv,
                                              int N) {
    __shared__ int rows[NPB * CAP];   // 20.5 KB
    __shared__ int cur[NPB];
    int b = blockIdx.x;
    int nbase = b * NPB;
    int nn = min(NPB, N - nbase);
    if (nn <= 0) return;
    for (int i = threadIdx.x; i < nn; i += 256) cur[i] = 0;
    __syncthreads();
    int s0 = b * SCAP, s1 = s0 + ecnt[b];
    for (int i = s0 + threadIdx.x; i < s1; i += 256) {
        int e  = staging[i];
        int vl = e >> 17;
        int u  = e & 0x1FFFF;
        int p  = atomicAdd(&cur[vl], 1);
        if (p < CAP) rows[vl * CAP + p] = u;
    }
    __syncthreads();
    for (int s = threadIdx.x; s < nn * CAP; s += 256) {
        int node = s / CAP, p = s - node * CAP;
        if (p < min(cur[node], CAP))
            adj[(size_t)(nbase + node) * CAP + p] = rows[s];
    }
    for (int i = threadIdx.x; i < nn; i += 256) {
        int c = cur[i];
        cnt[nbase + i]  = c;
        dinv[nbase + i] = rsqrtf(1.0f + (float)c);
    }
}

// ---------------- MFMA fused: h0 = relu(x@Wi+bi) (LDS, wave-private); out = f16((h0@W1)*dinv) ----------------
__global__ __launch_bounds__(256) void k_lin2(const float* __restrict__ x,
                                              const f16* __restrict__ WiT,
                                              const float* __restrict__ bi,
                                              const f16* __restrict__ W1T,
                                              const float* __restrict__ dinv,
                                              __half* __restrict__ out, int n) {
    __shared__ f16 h0[4 * 16 * 64];   // 8 KB, 2 KB per wave
    int t = threadIdx.x, lane = t & 63, w = t >> 6;
    int rb = blockIdx.x * 64 + w * 16;
    if (rb >= n) return;
    int lr = lane & 15;   // A/D row | B/D col
    int lg = lane >> 4;   // k-group / row-group
    f16x8 a[4];
    const float* xrow = x + (size_t)(rb + lr) * DIN + lg * 8;
#pragma unroll
    for (int k0 = 0; k0 < 4; k0++) {
        float4 f0 = *(const float4*)(xrow + k0 * 32);
        float4 f1 = *(const float4*)(xrow + k0 * 32 + 4);
        a[k0][0] = (f16)f0.x; a[k0][1] = (f16)f0.y; a[k0][2] = (f16)f0.z; a[k0][3] = (f16)f0.w;
        a[k0][4] = (f16)f1.x; a[k0][5] = (f16)f1.y; a[k0][6] = (f16)f1.z; a[k0][7] = (f16)f1.w;
    }
    char* hwb = (char*)(h0 + w * 16 * 64);
#pragma unroll
    for (int cb = 0; cb < 4; cb++) {
        f32x4 acc = {0.f, 0.f, 0.f, 0.f};
        const f16* wt = WiT + (cb * 16 + lr) * DIN + lg * 8;
#pragma unroll
        for (int k0 = 0; k0 < 4; k0++) {
            f16x8 bf = *(const f16x8*)(wt + k0 * 32);
            acc = __builtin_amdgcn_mfma_f32_16x16x32_f16(a[k0], bf, acc, 0, 0, 0);
        }
        float bv = bi[cb * 16 + lr];
#pragma unroll
        for (int r = 0; r < 4; r++) {
            int row = lg * 4 + r;
            *(f16*)(hwb + swz(row, (cb * 16 + lr) * 2)) = (f16)fmaxf(acc[r] + bv, 0.0f);
        }
    }
    f16x8 a2[2];
#pragma unroll
    for (int k0 = 0; k0 < 2; k0++)
        a2[k0] = *(const f16x8*)(hwb + swz(lr, k0 * 64 + lg * 16));
    float dv[4];
#pragma unroll
    for (int r = 0; r < 4; r++) dv[r] = dinv[rb + lg * 4 + r];
#pragma unroll
    for (int cb = 0; cb < 4; cb++) {
        f32x4 acc = {0.f, 0.f, 0.f, 0.f};
        const f16* wt = W1T + (cb * 16 + lr) * DH + lg * 8;
        acc = __builtin_amdgcn_mfma_f32_16x16x32_f16(a2[0], *(const f16x8*)(wt), acc, 0, 0, 0);
        acc = __builtin_amdgcn_mfma_f32_16x16x32_f16(a2[1], *(const f16x8*)(wt + 32), acc, 0, 0, 0);
#pragma unroll
        for (int r = 0; r < 4; r++)
            out[(size_t)(rb + lg * 4 + r) * DH + cb * 16 + lr] = __float2half(acc[r] * dv[r]);
    }
}

// ---------------- gather inner (round-12 proven form): 8 loads in flight ----------------
__device__ __forceinline__ void gather_node(int v, const int* __restrict__ cnt,
                                            const int* __restrict__ adj,
                                            const char* __restrict__ xb,
                                            int lane, int half_id, int fpo,
                                            float& ax, float& ay) {
    int len = min(cnt[v], CAP);
    const int* row = adj + (size_t)v * CAP;
    int idx = 0;
    if (lane < len) idx = row[lane];
    int len64 = min(len, 64);
    ax = 0.f; ay = 0.f;
    int k = half_id;
    for (; k + 14 < len64; k += 16) {
        int u0 = __shfl(idx, k);
        int u1 = __shfl(idx, k + 2);
        int u2 = __shfl(idx, k + 4);
        int u3 = __shfl(idx, k + 6);
        int u4 = __shfl(idx, k + 8);
        int u5 = __shfl(idx, k + 10);
        int u6 = __shfl(idx, k + 12);
        int u7 = __shfl(idx, k + 14);
        __half2 h0 = *(const __half2*)(xb + ((u0 << 7) | fpo));
        __half2 h1 = *(const __half2*)(xb + ((u1 << 7) | fpo));
        __half2 h2 = *(const __half2*)(xb + ((u2 << 7) | fpo));
        __half2 h3 = *(const __half2*)(xb + ((u3 << 7) | fpo));
        h0 = __hadd2(h0, *(const __half2*)(xb + ((u4 << 7) | fpo)));
        h1 = __hadd2(h1, *(const __half2*)(xb + ((u5 << 7) | fpo)));
        h2 = __hadd2(h2, *(const __half2*)(xb + ((u6 << 7) | fpo)));
        h3 = __hadd2(h3, *(const __half2*)(xb + ((u7 << 7) | fpo)));
        float2 f0 = __half22float2(h0);
        float2 f1 = __half22float2(h1);
        float2 f2 = __half22float2(h2);
        float2 f3 = __half22float2(h3);
        ax += (f0.x + f1.x) + (f2.x + f3.x);
        ay += (f0.y + f1.y) + (f2.y + f3.y);
    }
    for (; k < len64; k += 2) {
        int u0 = __shfl(idx, k);
        float2 f0 = __half22float2(*(const __half2*)(xb + ((u0 << 7) | fpo)));
        ax += f0.x; ay += f0.y;
    }
    for (int j = 64 + half_id; j < len; j += 2) {  // rare tail (deg > 64)
        float2 f0 = __half22float2(*(const __half2*)(xb + ((row[j] << 7) | fpo)));
        ax += f0.x; ay += f0.y;
    }
    ax += __shfl_xor(ax, 32);
    ay += __shfl_xor(ay, 32);
}

// ---------------- fused gather1 + conv2 matmul (4-wave blocks, 4 nodes/wave, shared tile) ----------------
__global__ __launch_bounds__(256) void k_g1(const int* __restrict__ cnt,
                                            const int* __restrict__ adj,
                                            const __half2* __restrict__ xws,
                                            const float* __restrict__ dinv,
                                            const float* __restrict__ b,
                                            const f16* __restrict__ W2T,
                                            __half* __restrict__ out, int n) {
    __shared__ char wb[2048];   // one shared 16-row x 128-B swizzled tile
    int t = threadIdx.x, lane = t & 63, w = t >> 6;
    int rb = blockIdx.x * 16;
    if (rb >= n) return;
    int half_id = lane >> 5, fp = lane & 31, fpo = fp << 2;
    const char* xb = (const char*)xws;
    float2 bb = ((const float2*)b)[fp];
#pragma unroll 1
    for (int i = 0; i < 4; i++) {
        int row = w * 4 + i;          // this wave's rows in the tile
        int v = rb + row;
        float ax, ay;
        gather_node(v, cnt, adj, xb, lane, half_id, fpo, ax, ay);
        if (half_id == 0) {
            float2 s  = __half22float2(*(const __half2*)(xb + ((v << 7) | fpo)));
            float  dv = dinv[v];
            __half2 hh = __floats2half2_rn(fmaxf(dv * (ax + s.x) + bb.x, 0.0f),
                                           fmaxf(dv * (ay + s.y) + bb.y, 0.0f));
            *(__half2*)(wb + swz(row, fpo)) = hh;
        }
    }
    __syncthreads();
    // MFMA phase: wave w computes column-block cb = w of the 16x64 tile
    int lr = lane & 15, lg = lane >> 4;
    f16x8 a0 = *(const f16x8*)(wb + swz(lr, lg * 16));
    f16x8 a1 = *(const f16x8*)(wb + swz(lr, 64 + lg * 16));
    float dvr[4];
#pragma unroll
    for (int r = 0; r < 4; r++) dvr[r] = dinv[rb + lg * 4 + r];
    int cb = w;
    const f16* wt = W2T + (cb * 16 + lr) * DH + lg * 8;
    f32x4 acc = {0.f, 0.f, 0.f, 0.f};
    acc = __builtin_amdgcn_mfma_f32_16x16x32_f16(a0, *(const f16x8*)(wt), acc, 0, 0, 0);
    acc = __builtin_amdgcn_mfma_f32_16x16x32_f16(a1, *(const f16x8*)(wt + 32), acc, 0, 0, 0);
#pragma unroll
    for (int r = 0; r < 4; r++)
        out[(size_t)(rb + lg * 4 + r) * DH + cb * 16 + lr] = __float2half(acc[r] * dvr[r]);
}

// ---------------- fused gather2 + pooling (1-wave blocks, 16-node runs — r14 proven) ----------------
__global__ __launch_bounds__(64) void k_g2(const int* __restrict__ cnt,
                                           const int* __restrict__ adj,
                                           const __half2* __restrict__ xws,
                                           const float* __restrict__ dinv,
                                           const float* __restrict__ b,
                                           const int* __restrict__ batch,
                                           float* __restrict__ sums,
                                           int* __restrict__ cnts, int n) {
    int lane = threadIdx.x & 63;
    int rb = blockIdx.x * 16;
    if (rb >= n) return;
    int half_id = lane >> 5, fp = lane & 31, fpo = fp << 2;
    const char* xb = (const char*)xws;
    float2 bb = ((const float2*)b)[fp];
    int curg = -1, c = 0;
    float pax = 0.f, pay = 0.f;
#pragma unroll 1
    for (int i = 0; i < 16; i++) {
        int v = rb + i;
        float ax, ay;
        gather_node(v, cnt, adj, xb, lane, half_id, fpo, ax, ay);
        float2 s  = __half22float2(*(const __half2*)(xb + ((v << 7) | fpo)));
        float  dv = dinv[v];
        float ox = fmaxf(dv * (ax + s.x) + bb.x, 0.0f);
        float oy = fmaxf(dv * (ay + s.y) + bb.y, 0.0f);
        int g = batch[v];
        if (g != curg) {
            if (curg >= 0 && half_id == 0) {
                atomicAdd(&sums[curg * DH + 2 * fp],     pax);
                atomicAdd(&sums[curg * DH + 2 * fp + 1], pay);
                if (lane == 0) atomicAdd(&cnts[curg], c);
            }
            curg = g; pax = 0.f; pay = 0.f; c = 0;
        }
        if (half_id == 0) { pax += ox; pay += oy; }
        c++;
    }
    if (curg >= 0 && half_id == 0) {
        atomicAdd(&sums[curg * DH + 2 * fp],     pax);
        atomicAdd(&sums[curg * DH + 2 * fp + 1], pay);
        if (lane == 0) atomicAdd(&cnts[curg], c);
    }
}

// ---------------- head: mean, fc1+relu, fc2, log_softmax ----------------
__global__ __launch_bounds__(64) void k_head(const float* __restrict__ sums,
                                             const int* __restrict__ cnts,
                                             const float* __restrict__ Wf1,
                                             const float* __restrict__ bf1,
                                             const float* __restrict__ Wf2,
                                             const float* __restrict__ bf2,
                                             float* __restrict__ out) {
    int g = blockIdx.x, lane = threadIdx.x;
    float cnt    = (float)max(cnts[g], 1);
    float pooled = sums[g * DH + lane] / cnt;
    float acc = (lane < DFC) ? bf1[lane] : 0.f;
    for (int k = 0; k < DH; k++) {
        float pk = __shfl(pooled, k);
        if (lane < DFC) acc = fmaf(pk, Wf1[k * DFC + lane], acc);
    }
    float gv = fmaxf(acc, 0.f);
    float acc2 = (lane < DC) ? bf2[lane] : 0.f;
    for (int k = 0; k < DFC; k++) {
        float gk = __shfl(gv, k);
        if (lane < DC) acc2 = fmaf(gk, Wf2[k * DC + lane], acc2);
    }
    float v = (lane < DC) ? acc2 : -INFINITY;
    float m = v;
    for (int o = 8; o; o >>= 1) m = fmaxf(m, __shfl_xor(m, o));
    float e = (lane < DC) ? expf(v - m) : 0.f;
    float s = e;
    for (int o = 8; o; o >>= 1) s += __shfl_xor(s, o);
    if (lane < DC) out[g * DC + lane] = v - m - logf(s);
}

extern "C" void kernel_launch(void* const* d_in, const int* in_sizes, int n_in,
                              void* d_out, int out_size, void* d_ws, size_t ws_size,
                              hipStream_t stream) {
    const float* x    = (const float*)d_in[0];
    const int*   ei   = (const int*)d_in[1];
    const int*   batch= (const int*)d_in[2];
    const float* W_in = (const float*)d_in[3];
    const float* b_in = (const float*)d_in[4];
    const float* W1   = (const float*)d_in[5];
    const float* b1   = (const float*)d_in[6];
    const float* W2   = (const float*)d_in[7];
    const float* b2   = (const float*)d_in[8];
    const float* Wf1  = (const float*)d_in[9];
    const float* bf1  = (const float*)d_in[10];
    const float* Wf2  = (const float*)d_in[11];
    const float* bf2  = (const float*)d_in[12];
    float* out = (float*)d_out;

    const int E = in_sizes[1] / 2;      // 1,600,000
    const int N = in_sizes[0] / DIN;    // 100,000
    const int* src = ei;
    const int* dst = ei + E;

    const int NBU = (N + NPB - 1) / NPB;        // buckets used (1563)
    const int EPB = (E + ABLK - 1) / ABLK;      // edges per hist/binplace block

    char* ws = (char*)d_ws;
    size_t off = 0;
    auto alloc = [&](size_t bytes) -> void* {
        void* p = ws + off;
        off = (off + bytes + 255) & ~(size_t)255;
        return p;
    };
    int*    cnt     = (int*)   alloc((size_t)N * 4);
    float*  dinv    = (float*) alloc((size_t)N * 4);
    int*    adj     = (int*)   alloc((size_t)N * CAP * 4);      // 32 MB
    int*    histT   = (int*)   alloc((size_t)NB * ABLK * 4);    // 1.6 MB
    int*    baseT   = (int*)   alloc((size_t)NB * ABLK * 4);    // 1.6 MB
    int*    ecnt    = (int*)   alloc((size_t)NB * 4);
    int*    staging = (int*)   alloc((size_t)NB * SCAP * 4);    // 16 MB
    __half* hA      = (__half*)alloc((size_t)N * DH * 2);       // 12.8 MB (xws2)
    __half* hX      = (__half*)alloc((size_t)N * DH * 2);       // 12.8 MB (xws1)
    float*  sums    = (float*) alloc((size_t)DG * DH * 4);
    int*    cnts    = (int*)   alloc((size_t)DG * 4);
    f16*    WiT     = (f16*)   alloc((size_t)DH * DIN * 2);
    f16*    W1T     = (f16*)   alloc((size_t)DH * DH * 2);
    f16*    W2T     = (f16*)   alloc((size_t)DH * DH * 2);

    // atomic-free adjacency build: hist(T) -> per-bucket scan(+pool zero +wprep) -> binplace -> rows
    k_hist<<<ABLK, 256, 0, stream>>>(src, dst, histT, E, EPB);
    k_expand<<<NB, 256, 0, stream>>>(histT, baseT, ecnt, sums, cnts,
                                     W_in, W1, W2, WiT, W1T, W2T);
    k_binplace<<<ABLK, 256, 0, stream>>>(src, dst, baseT, staging, E, EPB);
    k_rows<<<NBU, 256, 0, stream>>>(staging, ecnt, adj, cnt, dinv, N);

    // fused MFMA: h0 = relu(xWi+bi); xws1 = f16((h0@W1)*dinv)
    k_lin2<<<(N + 63) / 64, 256, 0, stream>>>(x, WiT, b_in, W1T, dinv, hX, N);

    // fused gather1 + conv2 matmul (4-wave blocks, 4 nodes/wave, shared 16-row tile)
    k_g1<<<(N + 15) / 16, 256, 0, stream>>>(cnt, adj, (const __half2*)hX, dinv, b1, W2T, hA, N);

    // fused gather2 + pooling (1-wave blocks, 16-node runs)
    k_g2<<<(N + 15) / 16, 64, 0, stream>>>(cnt, adj, (const __half2*)hA, dinv, b2, batch, sums, cnts, N);

    // head
    k_head<<<DG, 64, 0, stream>>>(sums, cnts, Wf1, bf1, Wf2, bf2, out);
}